// Round 1
// baseline (3039.323 us; speedup 1.0000x reference)
//
#include <hip/hip_runtime.h>
#include <hip/hip_bf16.h>

// ---------- types ----------
typedef short bf16v8 __attribute__((ext_vector_type(8)));
typedef float f32x4 __attribute__((ext_vector_type(4)));

// B=128, T=32, E=512, H=512, L=256, V=16000
// out regions: p_mu[4096x256], p_sig, q_mu, q_sig, q_x[4096x16000]

__device__ __forceinline__ void gload16(const void* g, void* l) {
    __builtin_amdgcn_global_load_lds(
        (const __attribute__((address_space(1))) void*)g,
        (__attribute__((address_space(3))) void*)l,
        16, 0, 0);
}

// ---------- bf16 MFMA GEMM: C[M][N] = A[M][K] * B[N][K]^T (+bias) ----------
// 128x128 tile, BK=32, 4 waves (2x2), each wave 64x64 = 4x4 frags of 16x16x32.
template<int SPLIT>
__global__ __launch_bounds__(256, 2) void gemm_bt(
    const __hip_bfloat16* __restrict__ A, int ldA,
    const __hip_bfloat16* __restrict__ B, int ldB,
    float* __restrict__ C, int ldC, float* __restrict__ C2,
    const float* __restrict__ bias,
    int K, int nTilesN)
{
    __shared__ __hip_bfloat16 As[128 * 32];
    __shared__ __hip_bfloat16 Bs[128 * 32];
    const int bid = blockIdx.x;
    const int bm = bid / nTilesN, bn = bid % nTilesN;
    const int m0 = bm * 128, n0 = bn * 128;
    const int tid = threadIdx.x, lane = tid & 63, wave = tid >> 6;
    const int wm = (wave & 1) * 64, wn = (wave >> 1) * 64;
    f32x4 acc[4][4] = {};

    // staging: chunk ci (1KB = 16 rows of 32 bf16); wave w stages chunks w, w+4
    const int ci0 = wave, ci1 = wave + 4;
    const int srow0 = ci0 * 16 + (lane >> 2);
    const int srow1 = ci1 * 16 + (lane >> 2);
    const int scol = (lane & 3) * 8;  // element offset
    const __hip_bfloat16* Ag0 = A + (size_t)(m0 + srow0) * ldA + scol;
    const __hip_bfloat16* Ag1 = A + (size_t)(m0 + srow1) * ldA + scol;
    const __hip_bfloat16* Bg0 = B + (size_t)(n0 + srow0) * ldB + scol;
    const __hip_bfloat16* Bg1 = B + (size_t)(n0 + srow1) * ldB + scol;
    char* AsB = (char*)As;
    char* BsB = (char*)Bs;
    const int fr = lane & 15, k0 = (lane >> 4) * 8;

    for (int kt = 0; kt < K; kt += 32) {
        gload16(Ag0 + kt, AsB + ci0 * 1024);
        gload16(Ag1 + kt, AsB + ci1 * 1024);
        gload16(Bg0 + kt, BsB + ci0 * 1024);
        gload16(Bg1 + kt, BsB + ci1 * 1024);
        __syncthreads();
        bf16v8 a[4], b[4];
        #pragma unroll
        for (int mi = 0; mi < 4; ++mi)
            a[mi] = *(const bf16v8*)(AsB + ((wm + mi * 16 + fr) * 32 + k0) * 2);
        #pragma unroll
        for (int ni = 0; ni < 4; ++ni)
            b[ni] = *(const bf16v8*)(BsB + ((wn + ni * 16 + fr) * 32 + k0) * 2);
        #pragma unroll
        for (int mi = 0; mi < 4; ++mi)
            #pragma unroll
            for (int ni = 0; ni < 4; ++ni)
                acc[mi][ni] = __builtin_amdgcn_mfma_f32_16x16x32_bf16(a[mi], b[ni], acc[mi][ni], 0, 0, 0);
        __syncthreads();
    }
    // epilogue: D row = (lane>>4)*4 + r, col = lane&15  [m89-verified]
    #pragma unroll
    for (int ni = 0; ni < 4; ++ni) {
        const int n = n0 + wn + ni * 16 + fr;
        const float bv = bias ? bias[n] : 0.f;
        #pragma unroll
        for (int mi = 0; mi < 4; ++mi) {
            #pragma unroll
            for (int r = 0; r < 4; ++r) {
                const int m = m0 + wm + mi * 16 + (lane >> 4) * 4 + r;
                const float v = acc[mi][ni][r] + bv;
                if (SPLIT) {
                    if (n < 256) C[(size_t)m * 256 + n] = v;
                    else         C2[(size_t)m * 256 + (n - 256)] = v;
                } else {
                    C[(size_t)m * ldC + n] = v;
                }
            }
        }
    }
}

// ---------- f32 recurrence: qz head ----------
// q = Qe[t] + h @ qz_W[:,512:].T + qz_b ; z = noise*q_sig + q_mu
// grid: 64 = 16 rowtiles(8 rows) x 4 ntiles(64 cols of mu, +256 for sigma)
__global__ __launch_bounds__(256) void qz_step_k(
    const float* __restrict__ h,
    const float* __restrict__ Qe_t,
    const float* __restrict__ qz_W,
    const float* __restrict__ qz_b,
    const float* __restrict__ noise,
    float* __restrict__ out_qmu_t,
    float* __restrict__ out_qsig_t,
    float* __restrict__ zf,
    __hip_bfloat16* __restrict__ XH_z,
    int t)
{
    __shared__ float2 Wms[64][33];
    __shared__ float xt[8][32];
    const int rt = (int)blockIdx.x >> 2, nt = (int)blockIdx.x & 3;
    const int r0 = rt * 8, n0 = nt * 64;
    const int tid = threadIdx.x, lane = tid & 63, wave = tid >> 6;
    float accm[2] = {0.f, 0.f}, accs[2] = {0.f, 0.f};
    for (int kt = 0; kt < 512; kt += 32) {
        #pragma unroll
        for (int j = 0; j < 8; ++j) {
            int e = tid + j * 256, nl = e >> 5, kl = e & 31;
            size_t col = 512 + kt + kl;
            Wms[nl][kl] = make_float2(qz_W[(size_t)(n0 + nl) * 1024 + col],
                                      qz_W[(size_t)(n0 + nl + 256) * 1024 + col]);
        }
        { int rl = tid >> 5, kl = tid & 31;
          xt[rl][kl] = h[(size_t)(r0 + rl) * 512 + kt + kl]; }
        __syncthreads();
        #pragma unroll 8
        for (int kk = 0; kk < 32; ++kk) {
            float2 w = Wms[lane][kk];
            #pragma unroll
            for (int i = 0; i < 2; ++i) {
                float hv = xt[wave * 2 + i][kk];
                accm[i] = fmaf(hv, w.x, accm[i]);
                accs[i] = fmaf(hv, w.y, accs[i]);
            }
        }
        __syncthreads();
    }
    const int c = n0 + lane;
    const float bm = qz_b[c], bs = qz_b[c + 256];
    #pragma unroll
    for (int i = 0; i < 2; ++i) {
        const int b = r0 + wave * 2 + i;
        float qm = accm[i] + Qe_t[(size_t)b * 512 + c] + bm;
        float qs = accs[i] + Qe_t[(size_t)b * 512 + c + 256] + bs;
        float nz = noise[((size_t)b * 32 + t) * 256 + c];
        float z = fmaf(nz, qs, qm);
        out_qmu_t[(size_t)b * 256 + c] = qm;
        out_qsig_t[(size_t)b * 256 + c] = qs;
        zf[(size_t)b * 256 + c] = z;
        XH_z[(size_t)b * 768 + c] = __float2bfloat16(z);
    }
}

// ---------- f32 recurrence: LSTM gates + state update ----------
// gates = Ge[t] + z@W_ih[:,512:].T + h@W_hh.T + (b_ih+b_hh); PyTorch order i,f,g,o
// grid: 128 = 16 rowtiles(8 rows) x 8 jtiles(64 cols, x4 gates)
template<bool INIT>
__global__ __launch_bounds__(256) void lstm_step_k(
    const float* __restrict__ xz, const float* __restrict__ hin,
    const float* __restrict__ cin,
    const float* __restrict__ W_ih, const float* __restrict__ W_hh,
    const float* __restrict__ b_ih, const float* __restrict__ b_hh,
    const float* __restrict__ Ge,
    float* __restrict__ hout, float* __restrict__ cout,
    __hip_bfloat16* __restrict__ XH_h)
{
    __shared__ float4 Wt4[64][33];
    __shared__ float xt[8][32];
    const int rt = (int)blockIdx.x >> 3, jt = (int)blockIdx.x & 7;
    const int r0 = rt * 8, j0 = jt * 64;
    const int tid = threadIdx.x, lane = tid & 63, wave = tid >> 6;
    float acc[4][2] = {};
    const int Kz = INIT ? 512 : 256;
    const int koff = INIT ? 0 : 512;
    for (int kt = 0; kt < Kz; kt += 32) {
        #pragma unroll
        for (int j = 0; j < 8; ++j) {
            int e = tid + j * 256, nl = e >> 5, kl = e & 31;
            size_t col = (size_t)koff + kt + kl;
            Wt4[nl][kl] = make_float4(
                W_ih[(size_t)(j0 + nl) * 768 + col],
                W_ih[(size_t)(j0 + nl + 512) * 768 + col],
                W_ih[(size_t)(j0 + nl + 1024) * 768 + col],
                W_ih[(size_t)(j0 + nl + 1536) * 768 + col]);
        }
        { int rl = tid >> 5, kl = tid & 31;
          xt[rl][kl] = xz[(size_t)(r0 + rl) * Kz + kt + kl]; }
        __syncthreads();
        #pragma unroll 8
        for (int kk = 0; kk < 32; ++kk) {
            float4 w = Wt4[lane][kk];
            #pragma unroll
            for (int i = 0; i < 2; ++i) {
                float xv = xt[wave * 2 + i][kk];
                acc[0][i] = fmaf(xv, w.x, acc[0][i]);
                acc[1][i] = fmaf(xv, w.y, acc[1][i]);
                acc[2][i] = fmaf(xv, w.z, acc[2][i]);
                acc[3][i] = fmaf(xv, w.w, acc[3][i]);
            }
        }
        __syncthreads();
    }
    if constexpr (!INIT) {
        for (int kt = 0; kt < 512; kt += 32) {
            #pragma unroll
            for (int j = 0; j < 8; ++j) {
                int e = tid + j * 256, nl = e >> 5, kl = e & 31;
                size_t col = (size_t)kt + kl;
                Wt4[nl][kl] = make_float4(
                    W_hh[(size_t)(j0 + nl) * 512 + col],
                    W_hh[(size_t)(j0 + nl + 512) * 512 + col],
                    W_hh[(size_t)(j0 + nl + 1024) * 512 + col],
                    W_hh[(size_t)(j0 + nl + 1536) * 512 + col]);
            }
            { int rl = tid >> 5, kl = tid & 31;
              xt[rl][kl] = hin[(size_t)(r0 + rl) * 512 + kt + kl]; }
            __syncthreads();
            #pragma unroll 8
            for (int kk = 0; kk < 32; ++kk) {
                float4 w = Wt4[lane][kk];
                #pragma unroll
                for (int i = 0; i < 2; ++i) {
                    float xv = xt[wave * 2 + i][kk];
                    acc[0][i] = fmaf(xv, w.x, acc[0][i]);
                    acc[1][i] = fmaf(xv, w.y, acc[1][i]);
                    acc[2][i] = fmaf(xv, w.z, acc[2][i]);
                    acc[3][i] = fmaf(xv, w.w, acc[3][i]);
                }
            }
            __syncthreads();
        }
    }
    const int jj = j0 + lane;
    #pragma unroll
    for (int i = 0; i < 2; ++i) {
        const int b = r0 + wave * 2 + i;
        float g0 = acc[0][i] + b_ih[jj] + b_hh[jj];
        float g1 = acc[1][i] + b_ih[jj + 512] + b_hh[jj + 512];
        float g2 = acc[2][i] + b_ih[jj + 1024] + b_hh[jj + 1024];
        float g3 = acc[3][i] + b_ih[jj + 1536] + b_hh[jj + 1536];
        if constexpr (!INIT) {
            const float* ge = Ge + (size_t)b * 2048;
            g0 += ge[jj]; g1 += ge[jj + 512]; g2 += ge[jj + 1024]; g3 += ge[jj + 1536];
        }
        float si = 1.f / (1.f + __expf(-g0));
        float sf = 1.f / (1.f + __expf(-g1));
        float tg = tanhf(g2);
        float so = 1.f / (1.f + __expf(-g3));
        float cold = INIT ? 0.f : cin[(size_t)b * 512 + jj];
        float cn = sf * cold + si * tg;
        float hn = so * tanhf(cn);
        cout[(size_t)b * 512 + jj] = cn;
        hout[(size_t)b * 512 + jj] = hn;
        XH_h[(size_t)b * 768 + jj] = __float2bfloat16(hn);
    }
}

// ---------- helpers ----------
__global__ void embed_k(const float* __restrict__ embW, const int* __restrict__ cap,
                        __hip_bfloat16* __restrict__ Emb) {
    const int row = blockIdx.x;  // t*128 + b
    const int t = row >> 7, b = row & 127;
    const int tok = cap[b * 32 + t];
    const float* src = embW + (size_t)tok * 512;
    __hip_bfloat16* dst = Emb + (size_t)row * 512;
    for (int k = threadIdx.x; k < 512; k += blockDim.x)
        dst[k] = __float2bfloat16(src[k]);
}

__global__ void conv_lin_k(const float* __restrict__ s, __hip_bfloat16* __restrict__ d, int n) {
    for (int i = blockIdx.x * blockDim.x + threadIdx.x; i < n; i += gridDim.x * blockDim.x)
        d[i] = __float2bfloat16(s[i]);
}

__global__ void conv_s512_k(const float* __restrict__ s, int ld, __hip_bfloat16* __restrict__ d, int n) {
    for (int i = blockIdx.x * blockDim.x + threadIdx.x; i < n; i += gridDim.x * blockDim.x) {
        int r = i >> 9, c = i & 511;
        d[i] = __float2bfloat16(s[(size_t)r * ld + c]);
    }
}

// ---------- fused log_softmax over rows of 16000 ----------
__global__ __launch_bounds__(256) void lse_k(float* __restrict__ logits) {
    __shared__ float buf[16000];
    __shared__ float red[4];
    const int row = blockIdx.x;
    const int tid = threadIdx.x;
    float* p = logits + (size_t)row * 16000;
    float mx = -3.4e38f;
    for (int i = tid; i < 16000; i += 256) { float v = p[i]; buf[i] = v; mx = fmaxf(mx, v); }
    #pragma unroll
    for (int o = 32; o; o >>= 1) mx = fmaxf(mx, __shfl_xor(mx, o));
    if ((tid & 63) == 0) red[tid >> 6] = mx;
    __syncthreads();
    mx = fmaxf(fmaxf(red[0], red[1]), fmaxf(red[2], red[3]));
    float s = 0.f;
    for (int i = tid; i < 16000; i += 256) s += __expf(buf[i] - mx);
    #pragma unroll
    for (int o = 32; o; o >>= 1) s += __shfl_xor(s, o);
    __syncthreads();
    if ((tid & 63) == 0) red[tid >> 6] = s;
    __syncthreads();
    const float lse = mx + logf(red[0] + red[1] + red[2] + red[3]);
    for (int i = tid; i < 16000; i += 256) p[i] = buf[i] - lse;
}

// ---------- launch ----------
extern "C" void kernel_launch(void* const* d_in, const int* in_sizes, int n_in,
                              void* d_out, int out_size, void* d_ws, size_t ws_size,
                              hipStream_t stream) {
    const float* features = (const float*)d_in[0];
    const int*   captions = (const int*)d_in[1];
    const float* noise    = (const float*)d_in[3];
    const float* embed_W  = (const float*)d_in[4];
    const float* W_ih     = (const float*)d_in[5];
    const float* W_hh     = (const float*)d_in[6];
    const float* b_ih     = (const float*)d_in[7];
    const float* b_hh     = (const float*)d_in[8];
    const float* qz_W     = (const float*)d_in[9];
    const float* qz_b     = (const float*)d_in[10];
    const float* prior_W  = (const float*)d_in[11];
    const float* prior_b  = (const float*)d_in[12];
    const float* qx_W     = (const float*)d_in[13];
    const float* qx_b     = (const float*)d_in[14];

    float* out0 = (float*)d_out;             // p_mus
    float* out1 = out0 + 4096 * 256;         // p_sigmas
    float* out2 = out1 + 4096 * 256;         // q_mus
    float* out3 = out2 + 4096 * 256;         // q_sigmas
    float* out4 = out3 + 4096 * 256;         // q_xs [4096][16000]

    char* ws = (char*)d_ws;
    __hip_bfloat16* qxWb  = (__hip_bfloat16*)(ws + 0);         // 16000x768
    __hip_bfloat16* Emb   = (__hip_bfloat16*)(ws + 24576000);  // 4096x512
    __hip_bfloat16* WihEb = (__hip_bfloat16*)(ws + 28770304);  // 2048x512
    __hip_bfloat16* qzWEb = (__hip_bfloat16*)(ws + 30867456);  // 512x512
    __hip_bfloat16* priWb = (__hip_bfloat16*)(ws + 31391744);  // 512x512
    __hip_bfloat16* XH    = (__hip_bfloat16*)(ws + 31916032);  // 4224x768 [z|h]
    float* Ge  = (float*)(ws + 38404096);   // 4096x2048
    float* Qe  = (float*)(ws + 71958528);   // 4096x512
    float* hb0 = (float*)(ws + 80347136);
    float* hb1 = (float*)(ws + 80609280);
    float* cb0 = (float*)(ws + 80871424);
    float* cb1 = (float*)(ws + 81133568);
    float* zf  = (float*)(ws + 81395712);   // 128x256

    conv_lin_k<<<2048, 256, 0, stream>>>(qx_W, qxWb, 16000 * 768);
    conv_lin_k<<<256, 256, 0, stream>>>(prior_W, priWb, 512 * 512);
    conv_s512_k<<<1024, 256, 0, stream>>>(W_ih, 768, WihEb, 2048 * 512);
    conv_s512_k<<<256, 256, 0, stream>>>(qz_W, 1024, qzWEb, 512 * 512);
    embed_k<<<4096, 256, 0, stream>>>(embed_W, captions, Emb);

    // Ge = Emb @ W_ih[:, :512].T   [4096 x 2048]
    gemm_bt<0><<<512, 256, 0, stream>>>(Emb, 512, WihEb, 512, Ge, 2048, nullptr, nullptr, 512, 16);
    // Qe = Emb @ qz_W[:, :512].T   [4096 x 512]
    gemm_bt<0><<<128, 256, 0, stream>>>(Emb, 512, qzWEb, 512, Qe, 512, nullptr, nullptr, 512, 4);

    // initial LSTM step: x0 = [features, 0]
    lstm_step_k<true><<<128, 256, 0, stream>>>(features, nullptr, nullptr, W_ih, W_hh,
                                               b_ih, b_hh, nullptr, hb0, cb0, XH + 256);

    for (int t = 0; t < 32; ++t) {
        float* hcur = (t & 1) ? hb1 : hb0;
        float* hnxt = (t & 1) ? hb0 : hb1;
        float* ccur = (t & 1) ? cb1 : cb0;
        float* cnxt = (t & 1) ? cb0 : cb1;
        qz_step_k<<<64, 256, 0, stream>>>(hcur, Qe + (size_t)t * 128 * 512, qz_W, qz_b, noise,
                                          out2 + (size_t)t * 128 * 256,
                                          out3 + (size_t)t * 128 * 256,
                                          zf, XH + (size_t)t * 128 * 768, t);
        lstm_step_k<false><<<128, 256, 0, stream>>>(zf, hcur, ccur, W_ih, W_hh, b_ih, b_hh,
                                                    Ge + (size_t)t * 128 * 2048, hnxt, cnxt,
                                                    XH + (size_t)(t + 1) * 128 * 768 + 256);
    }

    // prior: P = H @ prior_W.T + prior_b, split into p_mu / p_sigma
    gemm_bt<1><<<128, 256, 0, stream>>>(XH + 256, 768, priWb, 512, out0, 256, out1, prior_b, 512, 4);
    // logits: [Z|H] @ qx_W.T + qx_b  -> out4
    gemm_bt<0><<<4000, 256, 0, stream>>>(XH, 768, qxWb, 768, out4, 16000, nullptr, qx_b, 768, 125);
    // in-place log_softmax
    lse_k<<<4096, 256, 0, stream>>>(out4);
}